// Round 1
// baseline (226.376 us; speedup 1.0000x reference)
//
#include <hip/hip_runtime.h>
#include <stdint.h>

typedef int v4i __attribute__((ext_vector_type(4)));
typedef float float4_t __attribute__((ext_vector_type(4)));

#define K_DIM 1024
#define N_DIM 1024
#define BM 128
#define BN 128
#define BK 64

__device__ __forceinline__ void gload16(const void* g, void* l) {
  __builtin_amdgcn_global_load_lds(
      (const __attribute__((address_space(1))) unsigned int*)g,
      (__attribute__((address_space(3))) unsigned int*)l, 16, 0, 0);
}

// ---------------------------------------------------------------------------
// Kernel 1: per-token FWHT (== x @ H with H = Sylvester/sqrt(1024)) + 4-bit
// symmetric per-token quantization. 1 wave per token, 16 f32 per lane.
// Element mapping: e = rr*256 + lane*4 + c  (c=bits0-1, lane=bits2-7, rr=bits8-9)
// ---------------------------------------------------------------------------
__global__ __launch_bounds__(256) void fwht_quant_kernel(
    const float* __restrict__ x, int8_t* __restrict__ qx,
    float* __restrict__ ascale, int M) {
  const int lane = threadIdx.x & 63;
  const int wid = threadIdx.x >> 6;
  const long token = (long)blockIdx.x * 4 + wid;
  if (token >= M) return;
  const float* xr = x + token * K_DIM;

  float v[16];
  const float4_t* xr4 = (const float4_t*)xr;
#pragma unroll
  for (int rr = 0; rr < 4; ++rr) {
    float4_t f = xr4[rr * 64 + lane];
#pragma unroll
    for (int c = 0; c < 4; ++c) v[rr * 4 + c] = f[c];
  }
  // local stages: element strides 1,2 (bit c) and 256,512 (bit rr)
#pragma unroll
  for (int s = 1; s <= 2; s <<= 1) {
#pragma unroll
    for (int rr = 0; rr < 4; ++rr)
#pragma unroll
      for (int c = 0; c < 4; ++c)
        if ((c & s) == 0) {
          float a = v[rr * 4 + c], b = v[rr * 4 + (c | s)];
          v[rr * 4 + c] = a + b;
          v[rr * 4 + (c | s)] = a - b;
        }
  }
#pragma unroll
  for (int s = 1; s <= 2; s <<= 1) {
#pragma unroll
    for (int rr = 0; rr < 4; ++rr)
#pragma unroll
      for (int c = 0; c < 4; ++c)
        if ((rr & s) == 0) {
          float a = v[rr * 4 + c], b = v[(rr | s) * 4 + c];
          v[rr * 4 + c] = a + b;
          v[(rr | s) * 4 + c] = a - b;
        }
  }
  // cross-lane stages: element strides 4..128 -> lane masks 1..32
#pragma unroll
  for (int m = 1; m <= 32; m <<= 1) {
#pragma unroll
    for (int r = 0; r < 16; ++r) {
      float p = __shfl_xor(v[r], m, 64);
      v[r] = (lane & m) ? (p - v[r]) : (v[r] + p);
    }
  }
  // normalize (1/sqrt(1024)) + per-token absmax
  float mx = 0.f;
#pragma unroll
  for (int r = 0; r < 16; ++r) {
    v[r] *= 0.03125f;
    mx = fmaxf(mx, fabsf(v[r]));
  }
#pragma unroll
  for (int m = 32; m >= 1; m >>= 1) mx = fmaxf(mx, __shfl_xor(mx, m, 64));
  const float scale = fmaxf(mx, 1e-5f) / 7.0f;  // matches ref: clip(max,1e-5)/7
  if (lane == 0) ascale[token] = scale;

  int8_t* qr = qx + token * K_DIM;
#pragma unroll
  for (int rr = 0; rr < 4; ++rr) {
    int packed = 0;
#pragma unroll
    for (int c = 0; c < 4; ++c) {
      float q = rintf(v[rr * 4 + c] / scale);  // IEEE div + round-half-even, like ref
      q = fminf(7.f, fmaxf(-8.f, q));
      packed |= ((int)q & 0xff) << (8 * c);
    }
    *(int*)(qr + rr * 256 + lane * 4) = packed;
  }
}

// ---------------------------------------------------------------------------
// Kernel 2: per-row ternary weight quantization. 1 wave per row.
// ---------------------------------------------------------------------------
__global__ __launch_bounds__(256) void wquant_kernel(
    const float* __restrict__ w, int8_t* __restrict__ qw,
    float* __restrict__ wscale) {
  const int lane = threadIdx.x & 63;
  const int wid = threadIdx.x >> 6;
  const int row = blockIdx.x * 4 + wid;
  const float* wr = w + (long)row * K_DIM;

  float v[16];
  float s = 0.f;
  const float4_t* wr4 = (const float4_t*)wr;
#pragma unroll
  for (int rr = 0; rr < 4; ++rr) {
    float4_t f = wr4[rr * 64 + lane];
#pragma unroll
    for (int c = 0; c < 4; ++c) {
      v[rr * 4 + c] = f[c];
      s += fabsf(f[c]);
    }
  }
#pragma unroll
  for (int m = 32; m >= 1; m >>= 1) s += __shfl_xor(s, m, 64);
  const float scale = fmaxf(s * (1.0f / 1024.0f), 1e-5f);  // clip(mean,1e-5)
  if (lane == 0) wscale[row] = scale;

  int8_t* qr = qw + (long)row * K_DIM;
#pragma unroll
  for (int rr = 0; rr < 4; ++rr) {
    int packed = 0;
#pragma unroll
    for (int c = 0; c < 4; ++c) {
      float n = v[rr * 4 + c] / scale;
      int t = (n > 0.5f) ? 1 : ((n < -0.5f) ? -1 : 0);
      packed |= (t & 0xff) << (8 * c);
    }
    *(int*)(qr + rr * 256 + lane * 4) = packed;
  }
}

// ---------------------------------------------------------------------------
// Kernel 3: int8 GEMM  C[M][1024] = Aq[M][1024] . Bq[1024][1024]^T
// scaled by ascale[m]*wscale[n]. m97-structure: 128x128 tile, BK=64,
// 4 waves (2x2), global_load_lds width-16, mfma_i32_16x16x64_i8.
// ---------------------------------------------------------------------------
__global__ __launch_bounds__(256) void gemm_i8_kernel(
    const int8_t* __restrict__ A, const int8_t* __restrict__ B,
    const float* __restrict__ asc, const float* __restrict__ wsc,
    float* __restrict__ C, int M) {
  __shared__ int8_t Al[BM * BK];
  __shared__ int8_t Bl[BN * BK];
  const int bn = blockIdx.x & 7;   // 1024/128 = 8 col tiles
  const long bm = blockIdx.x >> 3;
  const int t = threadIdx.x;
  const int lane = t & 63;
  const int wm = (t >> 6) >> 1;    // wave row 0..1
  const int wn = (t >> 6) & 1;     // wave col 0..1

  // staging source: thread t covers tile-row t/4, k-bytes (t%4)*16
  const int8_t* gA = A + (bm * BM + (t >> 2)) * K_DIM + (t & 3) * 16;
  const int8_t* gB = B + ((long)bn * BN + (t >> 2)) * K_DIM + (t & 3) * 16;

  v4i acc[4][4] = {};
  const int rl = lane & 15;
  const int kb = lane >> 4;

  for (int ks = 0; ks < K_DIM; ks += BK) {
    gload16(gA + ks, Al + t * 16);
    gload16(gA + ks + 64 * K_DIM, Al + 4096 + t * 16);
    gload16(gB + ks, Bl + t * 16);
    gload16(gB + ks + 64 * K_DIM, Bl + 4096 + t * 16);
    __syncthreads();

    v4i a[4], b[4];
#pragma unroll
    for (int i = 0; i < 4; ++i)
      a[i] = *(const v4i*)(Al + (wm * 64 + i * 16 + rl) * BK + kb * 16);
#pragma unroll
    for (int j = 0; j < 4; ++j)
      b[j] = *(const v4i*)(Bl + (wn * 64 + j * 16 + rl) * BK + kb * 16);
#pragma unroll
    for (int i = 0; i < 4; ++i)
#pragma unroll
      for (int j = 0; j < 4; ++j)
        acc[i][j] = __builtin_amdgcn_mfma_i32_16x16x64_i8(a[i], b[j], acc[i][j], 0, 0, 0);
    __syncthreads();
  }

  // epilogue: C/D layout col=lane&15, row=(lane>>4)*4+reg
  const long row0 = bm * BM + wm * 64;
  const int col0 = bn * BN + wn * 64;
  const int lrow = (lane >> 4) * 4;
  const int lcol = lane & 15;
#pragma unroll
  for (int i = 0; i < 4; ++i) {
    float as[4];
#pragma unroll
    for (int r = 0; r < 4; ++r) as[r] = asc[row0 + i * 16 + lrow + r];
#pragma unroll
    for (int j = 0; j < 4; ++j) {
      const int col = col0 + j * 16 + lcol;
      const float ws = wsc[col];
#pragma unroll
      for (int r = 0; r < 4; ++r)
        C[(row0 + i * 16 + lrow + r) * (long)N_DIM + col] =
            (float)acc[i][j][r] * as[r] * ws;
    }
  }
}

// ---------------------------------------------------------------------------
extern "C" void kernel_launch(void* const* d_in, const int* in_sizes, int n_in,
                              void* d_out, int out_size, void* d_ws, size_t ws_size,
                              hipStream_t stream) {
  const float* x = (const float*)d_in[0];      // [8,8192,1024] f32
  const float* w = (const float*)d_in[1];      // [1024,1024] f32
  float* out = (float*)d_out;                  // [8,8192,1024] f32
  const int M = in_sizes[0] / K_DIM;           // 65536

  // workspace layout: qx (M*K i8) | qw (N*K i8) | ascale (M f32) | wscale (N f32)
  int8_t* qx = (int8_t*)d_ws;
  int8_t* qw = qx + (size_t)M * K_DIM;
  float* ascale = (float*)(qw + (size_t)N_DIM * K_DIM);
  float* wscale = ascale + M;

  fwht_quant_kernel<<<(M + 3) / 4, 256, 0, stream>>>(x, qx, ascale, M);
  wquant_kernel<<<N_DIM / 4, 256, 0, stream>>>(w, qw, wscale);
  gemm_i8_kernel<<<(M / BM) * (N_DIM / BN), 256, 0, stream>>>(qx, qw, ascale, wscale, out, M);
}

// Round 2
// 206.643 us; speedup vs baseline: 1.0955x; 1.0955x over previous
//
#include <hip/hip_runtime.h>
#include <stdint.h>

typedef int v4i __attribute__((ext_vector_type(4)));
typedef float float4_t __attribute__((ext_vector_type(4)));

#define K_DIM 1024
#define N_DIM 1024
#define BM 128
#define BN 128
#define BKB 128  // K-step in bytes (i8 elems) = 2 half-K subtiles of 64B

__device__ __forceinline__ void gload16(const void* g, void* l) {
  __builtin_amdgcn_global_load_lds(
      (const __attribute__((address_space(1))) unsigned int*)g,
      (__attribute__((address_space(3))) unsigned int*)l, 16, 0, 0);
}

// ---------------------------------------------------------------------------
// Kernel 1: per-token FWHT (== x @ H, H = Sylvester/sqrt(1024)) + 4-bit
// symmetric per-token quantization. 1 wave/token, 16 f32/lane.
// Element mapping: e = rr*256 + lane*4 + c
// ---------------------------------------------------------------------------
__global__ __launch_bounds__(256) void fwht_quant_kernel(
    const float* __restrict__ x, int8_t* __restrict__ qx,
    float* __restrict__ ascale, int M) {
  const int lane = threadIdx.x & 63;
  const int wid = threadIdx.x >> 6;
  const long token = (long)blockIdx.x * 4 + wid;
  if (token >= M) return;
  const float* xr = x + token * K_DIM;

  float v[16];
  const float4_t* xr4 = (const float4_t*)xr;
#pragma unroll
  for (int rr = 0; rr < 4; ++rr) {
    float4_t f = xr4[rr * 64 + lane];
#pragma unroll
    for (int c = 0; c < 4; ++c) v[rr * 4 + c] = f[c];
  }
  // local stages: strides 1,2 (bit c) and 256,512 (bit rr)
#pragma unroll
  for (int s = 1; s <= 2; s <<= 1) {
#pragma unroll
    for (int rr = 0; rr < 4; ++rr)
#pragma unroll
      for (int c = 0; c < 4; ++c)
        if ((c & s) == 0) {
          float a = v[rr * 4 + c], b = v[rr * 4 + (c | s)];
          v[rr * 4 + c] = a + b;
          v[rr * 4 + (c | s)] = a - b;
        }
  }
#pragma unroll
  for (int s = 1; s <= 2; s <<= 1) {
#pragma unroll
    for (int rr = 0; rr < 4; ++rr)
#pragma unroll
      for (int c = 0; c < 4; ++c)
        if ((rr & s) == 0) {
          float a = v[rr * 4 + c], b = v[(rr | s) * 4 + c];
          v[rr * 4 + c] = a + b;
          v[(rr | s) * 4 + c] = a - b;
        }
  }
  // cross-lane stages: strides 4..128 -> lane masks 1..32
#pragma unroll
  for (int m = 1; m <= 32; m <<= 1) {
#pragma unroll
    for (int r = 0; r < 16; ++r) {
      float p = __shfl_xor(v[r], m, 64);
      v[r] = (lane & m) ? (p - v[r]) : (v[r] + p);
    }
  }
  // absmax on UNnormalized values; fold 1/32 norm into the scale
  float mx = 0.f;
#pragma unroll
  for (int r = 0; r < 16; ++r) mx = fmaxf(mx, fabsf(v[r]));
#pragma unroll
  for (int m = 32; m >= 1; m >>= 1) mx = fmaxf(mx, __shfl_xor(mx, m, 64));
  const float scale = fmaxf(mx * 0.03125f, 1e-5f) * (1.0f / 7.0f);
  if (lane == 0) ascale[token] = scale;
  const float inv = 0.03125f / scale;  // one IEEE div; q = rint(v_un * inv)

  int8_t* qr = qx + token * K_DIM;
#pragma unroll
  for (int rr = 0; rr < 4; ++rr) {
    int packed = 0;
#pragma unroll
    for (int c = 0; c < 4; ++c) {
      float q = rintf(v[rr * 4 + c] * inv);
      q = fminf(7.f, fmaxf(-8.f, q));
      packed |= ((int)q & 0xff) << (8 * c);
    }
    *(int*)(qr + rr * 256 + lane * 4) = packed;
  }
}

// ---------------------------------------------------------------------------
// Kernel 2: per-row ternary weight quantization. 1 wave per row.
// ---------------------------------------------------------------------------
__global__ __launch_bounds__(256) void wquant_kernel(
    const float* __restrict__ w, int8_t* __restrict__ qw,
    float* __restrict__ wscale) {
  const int lane = threadIdx.x & 63;
  const int wid = threadIdx.x >> 6;
  const int row = blockIdx.x * 4 + wid;
  const float* wr = w + (long)row * K_DIM;

  float v[16];
  float s = 0.f;
  const float4_t* wr4 = (const float4_t*)wr;
#pragma unroll
  for (int rr = 0; rr < 4; ++rr) {
    float4_t f = wr4[rr * 64 + lane];
#pragma unroll
    for (int c = 0; c < 4; ++c) {
      v[rr * 4 + c] = f[c];
      s += fabsf(f[c]);
    }
  }
#pragma unroll
  for (int m = 32; m >= 1; m >>= 1) s += __shfl_xor(s, m, 64);
  const float scale = fmaxf(s * (1.0f / 1024.0f), 1e-5f);
  if (lane == 0) wscale[row] = scale;

  int8_t* qr = qw + (long)row * K_DIM;
#pragma unroll
  for (int rr = 0; rr < 4; ++rr) {
    int packed = 0;
#pragma unroll
    for (int c = 0; c < 4; ++c) {
      float n = v[rr * 4 + c] / scale;
      int t = (n > 0.5f) ? 1 : ((n < -0.5f) ? -1 : 0);
      packed |= (t & 0xff) << (8 * c);
    }
    *(int*)(qr + rr * 256 + lane * 4) = packed;
  }
}

// ---------------------------------------------------------------------------
// Kernel 3: int8 GEMM  C[M][1024] = Aq . Bq^T, scaled by ascale[m]*wscale[n].
// m97-equivalent structure: 128x128 tile, BK=128 i8 (=128B rows, byte-
// isomorphic to bf16 BK=64), 4 waves (2x2), global_load_lds width-16,
// mfma_i32_16x16x64_i8, 8 K-iterations.
// LDS layout: [ks2][row 0..127][64B] per operand -> keeps the conflict-free
// lane(kb,rl)->slot bijection of the 64B-row scheme (no swizzle needed;
// global per-lane source address absorbs the layout, LDS dest stays linear).
// ---------------------------------------------------------------------------
__global__ __launch_bounds__(256) void gemm_i8_kernel(
    const int8_t* __restrict__ A, const int8_t* __restrict__ B,
    const float* __restrict__ asc, const float* __restrict__ wsc,
    float* __restrict__ C, int M) {
  __shared__ int8_t Al[2 * BM * 64];
  __shared__ int8_t Bl[2 * BN * 64];
  const int bn = blockIdx.x & 7;   // 1024/128 = 8 col tiles
  const long bm = blockIdx.x >> 3;
  const int t = threadIdx.x;
  const int lane = t & 63;
  const int wm = (t >> 6) >> 1;    // wave row 0..1
  const int wn = (t >> 6) & 1;     // wave col 0..1

  // staging base: thread t covers tile-row t>>2, k-bytes (t&3)*16
  const int8_t* gA = A + (bm * BM + (t >> 2)) * (long)K_DIM + (t & 3) * 16;
  const int8_t* gB = B + ((long)bn * BN + (t >> 2)) * K_DIM + (t & 3) * 16;

  v4i acc[4][4] = {};
  const int rl = lane & 15;
  const int kb16 = (lane >> 4) * 16;

  for (int ks = 0; ks < K_DIM; ks += BKB) {
    // A tile: [ks2][128][64]  (16 KB), 4 passes of 256 thr x 16 B
    gload16(gA + ks, Al + t * 16);                            // ks2=0 rows 0-63
    gload16(gA + ks + 64 * K_DIM, Al + 4096 + t * 16);        // ks2=0 rows 64-127
    gload16(gA + ks + 64, Al + 8192 + t * 16);                // ks2=1 rows 0-63
    gload16(gA + ks + 64 * K_DIM + 64, Al + 12288 + t * 16);  // ks2=1 rows 64-127
    gload16(gB + ks, Bl + t * 16);
    gload16(gB + ks + 64 * K_DIM, Bl + 4096 + t * 16);
    gload16(gB + ks + 64, Bl + 8192 + t * 16);
    gload16(gB + ks + 64 * K_DIM + 64, Bl + 12288 + t * 16);
    __syncthreads();

#pragma unroll
    for (int ks2 = 0; ks2 < 2; ++ks2) {
      v4i a[4], b[4];
#pragma unroll
      for (int i = 0; i < 4; ++i)
        a[i] = *(const v4i*)(Al + ks2 * 8192 + (wm * 64 + i * 16 + rl) * 64 + kb16);
#pragma unroll
      for (int j = 0; j < 4; ++j)
        b[j] = *(const v4i*)(Bl + ks2 * 8192 + (wn * 64 + j * 16 + rl) * 64 + kb16);
#pragma unroll
      for (int i = 0; i < 4; ++i)
#pragma unroll
        for (int j = 0; j < 4; ++j)
          acc[i][j] = __builtin_amdgcn_mfma_i32_16x16x64_i8(a[i], b[j], acc[i][j], 0, 0, 0);
    }
    __syncthreads();
  }

  // epilogue: C/D layout col=lane&15, row=(lane>>4)*4+reg
  const long row0 = bm * BM + wm * 64;
  const int col0 = bn * BN + wn * 64;
  const int lrow = (lane >> 4) * 4;
  const int lcol = lane & 15;
#pragma unroll
  for (int i = 0; i < 4; ++i) {
    float as[4];
#pragma unroll
    for (int r = 0; r < 4; ++r) as[r] = asc[row0 + i * 16 + lrow + r];
#pragma unroll
    for (int j = 0; j < 4; ++j) {
      const int col = col0 + j * 16 + lcol;
      const float ws = wsc[col];
#pragma unroll
      for (int r = 0; r < 4; ++r)
        C[(row0 + i * 16 + lrow + r) * (long)N_DIM + col] =
            (float)acc[i][j][r] * as[r] * ws;
    }
  }
}

// ---------------------------------------------------------------------------
extern "C" void kernel_launch(void* const* d_in, const int* in_sizes, int n_in,
                              void* d_out, int out_size, void* d_ws, size_t ws_size,
                              hipStream_t stream) {
  const float* x = (const float*)d_in[0];      // [8,8192,1024] f32
  const float* w = (const float*)d_in[1];      // [1024,1024] f32
  float* out = (float*)d_out;                  // [8,8192,1024] f32
  const int M = in_sizes[0] / K_DIM;           // 65536

  // workspace: qx (M*K i8) | qw (N*K i8) | ascale (M f32) | wscale (N f32)
  int8_t* qx = (int8_t*)d_ws;
  int8_t* qw = qx + (size_t)M * K_DIM;
  float* ascale = (float*)(qw + (size_t)N_DIM * K_DIM);
  float* wscale = ascale + M;

  fwht_quant_kernel<<<(M + 3) / 4, 256, 0, stream>>>(x, qx, ascale, M);
  wquant_kernel<<<N_DIM / 4, 256, 0, stream>>>(w, qw, wscale);
  gemm_i8_kernel<<<(M / BM) * (N_DIM / BN), 256, 0, stream>>>(qx, qw, ascale, wscale, out, M);
}

// Round 3
// 205.104 us; speedup vs baseline: 1.1037x; 1.0075x over previous
//
#include <hip/hip_runtime.h>
#include <stdint.h>

typedef int v4i __attribute__((ext_vector_type(4)));
typedef float float4_t __attribute__((ext_vector_type(4)));

#define K_DIM 1024
#define N_DIM 1024
#define BM 256
#define BN 256
#define NKT 8           // K-tiles of 128 i8 each
#define TILEB (256 * 128)

__device__ __forceinline__ void gload16(const void* g, void* l) {
  __builtin_amdgcn_global_load_lds(
      (const __attribute__((address_space(1))) unsigned int*)g,
      (__attribute__((address_space(3))) unsigned int*)l, 16, 0, 0);
}

#define MFMA_I8 __builtin_amdgcn_mfma_i32_16x16x64_i8

// ---------------------------------------------------------------------------
// Kernel 1: per-token FWHT (== x @ H, H = Sylvester/sqrt(1024)) + 4-bit
// symmetric per-token quantization. 1 wave/token, 16 f32/lane. (unchanged)
// ---------------------------------------------------------------------------
__global__ __launch_bounds__(256) void fwht_quant_kernel(
    const float* __restrict__ x, int8_t* __restrict__ qx,
    float* __restrict__ ascale, int M) {
  const int lane = threadIdx.x & 63;
  const int wid = threadIdx.x >> 6;
  const long token = (long)blockIdx.x * 4 + wid;
  if (token >= M) return;
  const float* xr = x + token * K_DIM;

  float v[16];
  const float4_t* xr4 = (const float4_t*)xr;
#pragma unroll
  for (int rr = 0; rr < 4; ++rr) {
    float4_t f = xr4[rr * 64 + lane];
#pragma unroll
    for (int c = 0; c < 4; ++c) v[rr * 4 + c] = f[c];
  }
#pragma unroll
  for (int s = 1; s <= 2; s <<= 1) {
#pragma unroll
    for (int rr = 0; rr < 4; ++rr)
#pragma unroll
      for (int c = 0; c < 4; ++c)
        if ((c & s) == 0) {
          float a = v[rr * 4 + c], b = v[rr * 4 + (c | s)];
          v[rr * 4 + c] = a + b;
          v[rr * 4 + (c | s)] = a - b;
        }
  }
#pragma unroll
  for (int s = 1; s <= 2; s <<= 1) {
#pragma unroll
    for (int rr = 0; rr < 4; ++rr)
#pragma unroll
      for (int c = 0; c < 4; ++c)
        if ((rr & s) == 0) {
          float a = v[rr * 4 + c], b = v[(rr | s) * 4 + c];
          v[rr * 4 + c] = a + b;
          v[(rr | s) * 4 + c] = a - b;
        }
  }
#pragma unroll
  for (int m = 1; m <= 32; m <<= 1) {
#pragma unroll
    for (int r = 0; r < 16; ++r) {
      float p = __shfl_xor(v[r], m, 64);
      v[r] = (lane & m) ? (p - v[r]) : (v[r] + p);
    }
  }
  float mx = 0.f;
#pragma unroll
  for (int r = 0; r < 16; ++r) mx = fmaxf(mx, fabsf(v[r]));
#pragma unroll
  for (int m = 32; m >= 1; m >>= 1) mx = fmaxf(mx, __shfl_xor(mx, m, 64));
  const float scale = fmaxf(mx * 0.03125f, 1e-5f) * (1.0f / 7.0f);
  if (lane == 0) ascale[token] = scale;
  const float inv = 0.03125f / scale;

  int8_t* qr = qx + token * K_DIM;
#pragma unroll
  for (int rr = 0; rr < 4; ++rr) {
    int packed = 0;
#pragma unroll
    for (int c = 0; c < 4; ++c) {
      float q = rintf(v[rr * 4 + c] * inv);
      q = fminf(7.f, fmaxf(-8.f, q));
      packed |= ((int)q & 0xff) << (8 * c);
    }
    *(int*)(qr + rr * 256 + lane * 4) = packed;
  }
}

// ---------------------------------------------------------------------------
// Kernel 2: per-row ternary weight quantization. 1 wave per row. (unchanged)
// ---------------------------------------------------------------------------
__global__ __launch_bounds__(256) void wquant_kernel(
    const float* __restrict__ w, int8_t* __restrict__ qw,
    float* __restrict__ wscale) {
  const int lane = threadIdx.x & 63;
  const int wid = threadIdx.x >> 6;
  const int row = blockIdx.x * 4 + wid;
  const float* wr = w + (long)row * K_DIM;

  float v[16];
  float s = 0.f;
  const float4_t* wr4 = (const float4_t*)wr;
#pragma unroll
  for (int rr = 0; rr < 4; ++rr) {
    float4_t f = wr4[rr * 64 + lane];
#pragma unroll
    for (int c = 0; c < 4; ++c) {
      v[rr * 4 + c] = f[c];
      s += fabsf(f[c]);
    }
  }
#pragma unroll
  for (int m = 32; m >= 1; m >>= 1) s += __shfl_xor(s, m, 64);
  const float scale = fmaxf(s * (1.0f / 1024.0f), 1e-5f);
  if (lane == 0) wscale[row] = scale;

  int8_t* qr = qw + (long)row * K_DIM;
#pragma unroll
  for (int rr = 0; rr < 4; ++rr) {
    int packed = 0;
#pragma unroll
    for (int c = 0; c < 4; ++c) {
      float n = v[rr * 4 + c] / scale;
      int t = (n > 0.5f) ? 1 : ((n < -0.5f) ? -1 : 0);
      packed |= (t & 0xff) << (8 * c);
    }
    *(int*)(qr + rr * 256 + lane * 4) = packed;
  }
}

// ---------------------------------------------------------------------------
// Kernel 3: int8 GEMM, 256x256 8-phase schedule (m201 template, i8 port).
// - 8 waves (2M x 4N), 512 thr; per-wave 128x64 output; acc v4i[8][4].
// - K-tile = 128 B/row; 2 k-substeps of 64; 4 phases/tile x 16 MFMA.
// - LDS 128 KiB: A[2]/B[2] x 32 KiB, [256 rows][128 B] linear rows.
// - T2 swizzle: row r, 16B-slot s holds logical k-chunk s^(r&7). Staged via
//   inverse-swizzled per-lane GLOBAL source (linear LDS dest, rule #21);
//   ds_read applies the same XOR -> 2-way bank aliasing (free).
// - T3/T4: staging 2 tiles ahead, 8 gloads/tile/wave, vmcnt(8) only at tile
//   boundaries; raw s_barrier (never __syncthreads -> would drain vmcnt).
// - T5: setprio(1) around each 16-MFMA cluster.  T1: XCD swizzle (1024%8==0).
// ---------------------------------------------------------------------------
__global__ __launch_bounds__(512, 2) void gemm_i8_kernel(
    const int8_t* __restrict__ A, const int8_t* __restrict__ B,
    const float* __restrict__ asc, const float* __restrict__ wsc,
    float* __restrict__ C, int M) {
  __shared__ int8_t Al[2][TILEB];
  __shared__ int8_t Bl[2][TILEB];

  const int t = threadIdx.x;
  const int lane = t & 63;
  const int wid = t >> 6;
  const int wm = wid >> 2;  // 0..1
  const int wn = wid & 3;   // 0..3
  const int rl = lane & 15;
  const int kb = lane >> 4;

  // T1: XCD swizzle. grid=1024, 8 XCDs, 128 blocks/XCD chunk.
  const int swz = (blockIdx.x & 7) * 128 + (blockIdx.x >> 3);
  const long bm = swz >> 2;  // 0..255
  const int bn = swz & 3;    // 0..3

  // staging: statement s covers rows s*64 + (t>>3), slot t&7; global k-chunk
  // inverse-swizzled: (t&7) ^ ((t>>3)&7). LDS dest = buf + s*8192 + t*16.
  const int chunkoff = (((t & 7) ^ ((t >> 3) & 7)) << 4);
  const int8_t* gA = A + (bm * BM + (t >> 3)) * (long)K_DIM + chunkoff;
  const int8_t* gB = B + ((long)bn * BN + (t >> 3)) * K_DIM + chunkoff;

  // frag-read offsets (swizzled): logical chunk = ks2*4+kb, phys = ^(rl&7)
  const int swz0 = ((kb ^ (rl & 7)) << 4);
  const int swz1 = (((4 + kb) ^ (rl & 7)) << 4);
  const int aoff = (wm * 128 + rl) * 128;
  const int boff = (wn * 64 + rl) * 128;

  v4i acc[8][4] = {};

#define STAGE4(gbase, buf, koff)                                     \
  gload16((gbase) + (koff), (buf) + t * 16);                         \
  gload16((gbase) + 64 * K_DIM + (koff), (buf) + 8192 + t * 16);     \
  gload16((gbase) + 128 * K_DIM + (koff), (buf) + 16384 + t * 16);   \
  gload16((gbase) + 192 * K_DIM + (koff), (buf) + 24576 + t * 16);

  // prologue: fully stage tiles 0 and 1 (16 gloads/wave)
  STAGE4(gA, &Al[0][0], 0);
  STAGE4(gB, &Bl[0][0], 0);
  STAGE4(gA, &Al[1][0], 128);
  STAGE4(gB, &Bl[1][0], 128);
  asm volatile("s_waitcnt vmcnt(8)" ::: "memory");  // tile0 landed, tile1 in flight
  asm volatile("s_barrier" ::: "memory");

  for (int kt = 0; kt < NKT; ++kt) {
    const int p = kt & 1;
    const int8_t* Ab = &Al[p][0];
    const int8_t* Bb = &Bl[p][0];
    const bool pre = (kt + 2) < NKT;
    const int kfo = (kt + 2) * 128;

    v4i b[4][2], a[2][2];

    // ---- phase 0: all B frags + A f0,f1; MFMA quadrant 0
#pragma unroll
    for (int n = 0; n < 4; ++n) {
      b[n][0] = *(const v4i*)(Bb + n * 2048 + boff + swz0);
      b[n][1] = *(const v4i*)(Bb + n * 2048 + boff + swz1);
    }
#pragma unroll
    for (int f = 0; f < 2; ++f) {
      a[f][0] = *(const v4i*)(Ab + f * 2048 + aoff + swz0);
      a[f][1] = *(const v4i*)(Ab + f * 2048 + aoff + swz1);
    }
    asm volatile("s_barrier" ::: "memory");
    __builtin_amdgcn_s_setprio(1);
#pragma unroll
    for (int f = 0; f < 2; ++f)
#pragma unroll
      for (int n = 0; n < 4; ++n)
#pragma unroll
        for (int ks = 0; ks < 2; ++ks)
          acc[f][n] = MFMA_I8(a[f][ks], b[n][ks], acc[f][n], 0, 0, 0);
    __builtin_amdgcn_s_setprio(0);
    asm volatile("s_barrier" ::: "memory");

    // ---- phase 1: A f2,f3; stage B[kt+2] rows 0-127 (B[p] retired in ph0)
#pragma unroll
    for (int f = 0; f < 2; ++f) {
      a[f][0] = *(const v4i*)(Ab + (2 + f) * 2048 + aoff + swz0);
      a[f][1] = *(const v4i*)(Ab + (2 + f) * 2048 + aoff + swz1);
    }
    if (pre) {
      gload16(gB + kfo, &Bl[p][0] + t * 16);
      gload16(gB + 64 * K_DIM + kfo, &Bl[p][0] + 8192 + t * 16);
    }
    asm volatile("s_barrier" ::: "memory");
    __builtin_amdgcn_s_setprio(1);
#pragma unroll
    for (int f = 0; f < 2; ++f)
#pragma unroll
      for (int n = 0; n < 4; ++n)
#pragma unroll
        for (int ks = 0; ks < 2; ++ks)
          acc[2 + f][n] = MFMA_I8(a[f][ks], b[n][ks], acc[2 + f][n], 0, 0, 0);
    __builtin_amdgcn_s_setprio(0);
    asm volatile("s_barrier" ::: "memory");

    // ---- phase 2: A f4,f5; stage B[kt+2] rows 128-255
#pragma unroll
    for (int f = 0; f < 2; ++f) {
      a[f][0] = *(const v4i*)(Ab + (4 + f) * 2048 + aoff + swz0);
      a[f][1] = *(const v4i*)(Ab + (4 + f) * 2048 + aoff + swz1);
    }
    if (pre) {
      gload16(gB + 128 * K_DIM + kfo, &Bl[p][0] + 16384 + t * 16);
      gload16(gB + 192 * K_DIM + kfo, &Bl[p][0] + 24576 + t * 16);
    }
    asm volatile("s_barrier" ::: "memory");
    __builtin_amdgcn_s_setprio(1);
#pragma unroll
    for (int f = 0; f < 2; ++f)
#pragma unroll
      for (int n = 0; n < 4; ++n)
#pragma unroll
        for (int ks = 0; ks < 2; ++ks)
          acc[4 + f][n] = MFMA_I8(a[f][ks], b[n][ks], acc[4 + f][n], 0, 0, 0);
    __builtin_amdgcn_s_setprio(0);
    asm volatile("s_barrier" ::: "memory");

    // ---- phase 3: A f6,f7; barrier; stage A[kt+2] (A[p] reads all issued);
    //      MFMA quadrant 3; boundary vmcnt; barrier
#pragma unroll
    for (int f = 0; f < 2; ++f) {
      a[f][0] = *(const v4i*)(Ab + (6 + f) * 2048 + aoff + swz0);
      a[f][1] = *(const v4i*)(Ab + (6 + f) * 2048 + aoff + swz1);
    }
    asm volatile("s_barrier" ::: "memory");
    if (pre) {
      STAGE4(gA, &Al[p][0], kfo);
    }
    __builtin_amdgcn_s_setprio(1);
#pragma unroll
    for (int f = 0; f < 2; ++f)
#pragma unroll
      for (int n = 0; n < 4; ++n)
#pragma unroll
        for (int ks = 0; ks < 2; ++ks)
          acc[6 + f][n] = MFMA_I8(a[f][ks], b[n][ks], acc[6 + f][n], 0, 0, 0);
    __builtin_amdgcn_s_setprio(0);
    if (pre) {
      asm volatile("s_waitcnt vmcnt(8)" ::: "memory");  // next tile landed
    } else {
      asm volatile("s_waitcnt vmcnt(0)" ::: "memory");
    }
    asm volatile("s_barrier" ::: "memory");
  }
#undef STAGE4

  // epilogue: C/D layout col=lane&15, row=(lane>>4)*4+reg
  const long row0 = bm * BM + wm * 128;
  const int col0 = bn * BN + wn * 64;
  const int lrow = kb * 4;
#pragma unroll
  for (int f = 0; f < 8; ++f) {
    float as[4];
#pragma unroll
    for (int r = 0; r < 4; ++r) as[r] = asc[row0 + f * 16 + lrow + r];
#pragma unroll
    for (int n = 0; n < 4; ++n) {
      const int col = col0 + n * 16 + rl;
      const float ws = wsc[col];
#pragma unroll
      for (int r = 0; r < 4; ++r)
        C[(row0 + f * 16 + lrow + r) * (long)N_DIM + col] =
            (float)acc[f][n][r] * as[r] * ws;
    }
  }
}

// ---------------------------------------------------------------------------
extern "C" void kernel_launch(void* const* d_in, const int* in_sizes, int n_in,
                              void* d_out, int out_size, void* d_ws, size_t ws_size,
                              hipStream_t stream) {
  const float* x = (const float*)d_in[0];  // [8,8192,1024] f32
  const float* w = (const float*)d_in[1];  // [1024,1024] f32
  float* out = (float*)d_out;              // [8,8192,1024] f32
  const int M = in_sizes[0] / K_DIM;       // 65536

  int8_t* qx = (int8_t*)d_ws;
  int8_t* qw = qx + (size_t)M * K_DIM;
  float* ascale = (float*)(qw + (size_t)N_DIM * K_DIM);
  float* wscale = ascale + M;

  fwht_quant_kernel<<<(M + 3) / 4, 256, 0, stream>>>(x, qx, ascale, M);
  wquant_kernel<<<N_DIM / 4, 256, 0, stream>>>(w, qw, wscale);
  gemm_i8_kernel<<<(M / BM) * (N_DIM / BN), 512, 0, stream>>>(qx, qw, ascale, wscale, out, M);
}